// Round 10
// baseline (220.364 us; speedup 1.0000x reference)
//
#include <hip/hip_runtime.h>
#include <hip/hip_fp16.h>

typedef _Float16 f16x8 __attribute__((ext_vector_type(8)));
typedef float f32x4 __attribute__((ext_vector_type(4)));

// B=64, T=2000, E=512, D=1024, CC=32, K=31, H=128, PAD=15

__device__ __forceinline__ unsigned short f2h(float f) {
  __half h = __float2half(f);   // v_cvt_f16_f32, RNE
  return __builtin_bit_cast(unsigned short, h);
}

__device__ __forceinline__ f16x8 u4_to_f16x8(uint4 v) {
  return __builtin_bit_cast(f16x8, v);
}

__device__ __forceinline__ f16x8 cvt8(float4 u, float4 v) {
  uint4 w;
  w.x = ((unsigned)f2h(u.y) << 16) | f2h(u.x);
  w.y = ((unsigned)f2h(u.w) << 16) | f2h(u.z);
  w.z = ((unsigned)f2h(v.y) << 16) | f2h(v.x);
  w.w = ((unsigned)f2h(v.w) << 16) | f2h(v.z);
  return u4_to_f16x8(w);
}

__device__ __forceinline__ float fast_tanh(float x) {
  return 1.f - 2.f / (__expf(2.f * x) + 1.f);   // max err ~1e-6, saturates correctly
}

// ---------------- prep: decb (fp32), MTg (f16 M^T, k-padded 32), WTpack (fragment-major f16 W_enc^T) ----------------
// WTpack: fragment (kc,ks,nt) contiguous 1 KB; lane L holds bytes [L*16, L*16+16):
//   element j of lane (lr=L&15, lg=L>>4) = W_enc[e][h], e=kc*64+ks*32+lg*8+j, h=nt*16+lr.
__global__ __launch_bounds__(256) void prep_kernel(
    const float* __restrict__ dec_state, const float* __restrict__ W_dec,
    const float* __restrict__ b_enc, const float* __restrict__ conv_w,
    const float* __restrict__ W_att, const float* __restrict__ W_enc,
    float* __restrict__ decb, unsigned short* __restrict__ MTg,
    unsigned short* __restrict__ WTpack)
{
  const int blk = blockIdx.x, tid = threadIdx.x;
  if (blk < 32) {
    __shared__ float sd[2048];
    const int sub = tid >> 7, h = tid & 127;
    const int b = blk*2 + sub;
    for (int i = h; i < 1024; i += 128) sd[sub*1024 + i] = dec_state[b*1024 + i];
    __syncthreads();
    float acc = b_enc[h];
    #pragma unroll 8
    for (int d = 0; d < 1024; ++d) acc = fmaf(sd[sub*1024 + d], W_dec[d*128 + h], acc);
    decb[b*128 + h] = acc;
  } else if (blk < 96) {
    const int e0 = (blk - 32) * 8;
    #pragma unroll
    for (int jj = 0; jj < 4; ++jj) {
      int idx = tid + jj*256;
      int el = idx >> 7, hh = idx & 127;
      int e = e0 + el;
      int kc = e >> 6, ks = (e >> 5) & 1, lg = (e >> 3) & 3, j = e & 7;
      int nt = hh >> 4, lr = hh & 15;
      int dst = (((kc*2 + ks)*8 + nt)*64 + lg*16 + lr)*8 + j;
      WTpack[dst] = f2h(W_enc[e*128 + hh]);
    }
  } else {
    if (tid < 128) {
      const int h = tid;
      for (int k = 0; k < 31; ++k) {
        float a = 0.f;
        #pragma unroll
        for (int c = 0; c < 32; ++c) a = fmaf(conv_w[c*31 + k], W_att[c*128 + h], a);
        MTg[h*32 + k] = f2h(a);
      }
      MTg[h*32 + 31] = 0;   // zero pad -> conv MFMA K=32 exact
    }
  }
}

// ---------------- energy: 1 M-tile (16 rows) per wave, barrier-free, max-occupancy ----------------
// Issue order per kc: [16 B-loads (L2)] [cvt current A] [4 A-next loads (HBM), LAST] [16 MFMA].
// MFMAs wait vmcnt(4): B done, A-next still in flight -> A latency spans the whole next kc.
// acc[8] = 32 regs; launch_bounds(256,4) -> 128-reg budget -> 16 waves/CU (2x r9's 8).
__global__ __launch_bounds__(256, 4) void energy_kernel(
    const float* __restrict__ enc, const float* __restrict__ prev,
    const unsigned short* __restrict__ WTpack, const unsigned short* __restrict__ MTg,
    const float* __restrict__ decb, const float* __restrict__ W_out,
    float* __restrict__ energy)
{
  __shared__ float sPrev[96];
  __shared__ float sDecb[128];
  __shared__ float sWout[128];

  const int b  = blockIdx.y;
  const int t0 = blockIdx.x * 64;
  const int tid = threadIdx.x;
  const int wave = tid >> 6, lane = tid & 63;
  const int lr = lane & 15, lg = lane >> 4;

  if (tid < 128) { sDecb[tid] = decb[b*128 + tid]; sWout[tid] = W_out[tid]; }
  if (tid < 96) {
    int tt = t0 + tid - 15;
    sPrev[tid] = (tt >= 0 && tt < 2000) ? prev[b*2000 + tt] : 0.f;
  }
  __syncthreads();   // only barrier; waves independent afterwards

  const float* encB = enc + (size_t)b * (2000u*512u);
  int tg = t0 + wave*16 + lr; if (tg > 1999) tg = 1999;   // clamp; rows>=2000 never written
  const float* rowp = encB + (size_t)tg*512 + lg*8;
  const char* wp = (const char*)WTpack + lane*16;

  f32x4 acc[8];
  #pragma unroll
  for (int i = 0; i < 8; ++i) acc[i] = (f32x4){0,0,0,0};

  // prologue: A(kc=0)
  float4 c0 = *reinterpret_cast<const float4*>(rowp + 0);
  float4 c1 = *reinterpret_cast<const float4*>(rowp + 4);
  float4 c2 = *reinterpret_cast<const float4*>(rowp + 32);
  float4 c3 = *reinterpret_cast<const float4*>(rowp + 36);

  #pragma unroll
  for (int kc = 0; kc < 8; ++kc) {
    // (1) all B loads for this kc (L2-hot), issued first
    uint4 rb0[8], rb1[8];
    #pragma unroll
    for (int nt = 0; nt < 8; ++nt)
      rb0[nt] = *reinterpret_cast<const uint4*>(wp + ((kc*2 + 0)*8 + nt)*1024);
    #pragma unroll
    for (int nt = 0; nt < 8; ++nt)
      rb1[nt] = *reinterpret_cast<const uint4*>(wp + ((kc*2 + 1)*8 + nt)*1024);
    // (2) convert current A (waits only on A(kc), issued last iteration)
    f16x8 a0 = cvt8(c0, c1);   // ks=0
    f16x8 a1 = cvt8(c2, c3);   // ks=1
    // (3) A-next issued LAST -> B-waits below leave it outstanding (vmcnt(4))
    if (kc < 7) {
      const float* p = rowp + (kc+1)*64;
      c0 = *reinterpret_cast<const float4*>(p + 0);
      c1 = *reinterpret_cast<const float4*>(p + 4);
      c2 = *reinterpret_cast<const float4*>(p + 32);
      c3 = *reinterpret_cast<const float4*>(p + 36);
    }
    // (4) MFMAs
    #pragma unroll
    for (int nt = 0; nt < 8; ++nt)
      acc[nt] = __builtin_amdgcn_mfma_f32_16x16x32_f16(a0, u4_to_f16x8(rb0[nt]), acc[nt], 0, 0, 0);
    #pragma unroll
    for (int nt = 0; nt < 8; ++nt)
      acc[nt] = __builtin_amdgcn_mfma_f32_16x16x32_f16(a1, u4_to_f16x8(rb1[nt]), acc[nt], 0, 0, 0);
  }

  // conv as MFMA (r6-r9: identical 4.88e-4 floor as fp32 conv)
  {
    f16x8 a2;
    const int pb0 = wave*16 + lr + lg*8;
    #pragma unroll
    for (int j = 0; j < 8; ++j)
      a2[j] = __builtin_bit_cast(_Float16, f2h(sPrev[pb0 + j]));
    const char* mb = (const char*)MTg + lr*64 + lg*16;
    #pragma unroll
    for (int nt = 0; nt < 8; ++nt) {
      uint4 mv = *reinterpret_cast<const uint4*>(mb + nt*1024);
      acc[nt] = __builtin_amdgcn_mfma_f32_16x16x32_f16(a2, u4_to_f16x8(mv), acc[nt], 0, 0, 0);
    }
  }

  // epilogue: + dec, tanh, dot W_out, reduce over h (lr)
  {
    float es0 = 0.f, es1 = 0.f, es2 = 0.f, es3 = 0.f;
    #pragma unroll
    for (int nt = 0; nt < 8; ++nt) {
      float dh = sDecb[nt*16 + lr];
      float wo = sWout[nt*16 + lr];
      es0 += fast_tanh(acc[nt][0] + dh) * wo;
      es1 += fast_tanh(acc[nt][1] + dh) * wo;
      es2 += fast_tanh(acc[nt][2] + dh) * wo;
      es3 += fast_tanh(acc[nt][3] + dh) * wo;
    }
    #pragma unroll
    for (int off = 1; off < 16; off <<= 1) {
      es0 += __shfl_xor(es0, off, 64);
      es1 += __shfl_xor(es1, off, 64);
      es2 += __shfl_xor(es2, off, 64);
      es3 += __shfl_xor(es3, off, 64);
    }
    if (lr == 0) {
      const int t = t0 + wave*16 + lg*4;
      float ev[4] = {es0, es1, es2, es3};
      #pragma unroll
      for (int r = 0; r < 4; ++r)
        if (t + r < 2000) energy[b*2000 + t + r] = ev[r];
    }
  }
}

// ---------------- softmax over T per b -> att_w ----------------
__global__ __launch_bounds__(256) void softmax_kernel(
    const float* __restrict__ energy, float* __restrict__ attw)
{
  const int b = blockIdx.x, tid = threadIdx.x;
  __shared__ float red[4];
  __shared__ float red2[4];
  float m = -1e30f;
  for (int i = tid; i < 2000; i += 256) m = fmaxf(m, energy[b*2000 + i]);
  #pragma unroll
  for (int off = 1; off < 64; off <<= 1) m = fmaxf(m, __shfl_xor(m, off, 64));
  if ((tid & 63) == 0) red[tid >> 6] = m;
  __syncthreads();
  m = fmaxf(fmaxf(red[0], red[1]), fmaxf(red[2], red[3]));

  float s = 0.f;
  for (int i = tid; i < 2000; i += 256) {
    float p = __expf(energy[b*2000 + i] - m);
    attw[b*2000 + i] = p;
    s += p;
  }
  #pragma unroll
  for (int off = 1; off < 64; off <<= 1) s += __shfl_xor(s, off, 64);
  if ((tid & 63) == 0) red2[tid >> 6] = s;
  __syncthreads();
  s = red2[0] + red2[1] + red2[2] + red2[3];
  float inv = 1.f / s;
  for (int i = tid; i < 2000; i += 256) attw[b*2000 + i] *= inv;
}

// ---------------- att_c partials: float4 loads, t-parity split (32 partials/b) ----------------
__global__ __launch_bounds__(256) void attc_partial_kernel(
    const float* __restrict__ enc, const float* __restrict__ attw,
    float* __restrict__ part)
{
  const int b = blockIdx.y, ch = blockIdx.x, tid = threadIdx.x;
  const int p = tid >> 7;
  const int e4 = (tid & 127) * 4;
  const int tstart = ch * 125 + p, tend = ch * 125 + 125;
  const float* encB = enc + (size_t)b * (2000u*512u);
  float a0 = 0.f, a1 = 0.f, a2 = 0.f, a3 = 0.f;
  #pragma unroll 2
  for (int t = tstart; t < tend; t += 2) {
    float w = attw[b*2000 + t];
    float4 v = *reinterpret_cast<const float4*>(encB + (size_t)t*512 + e4);
    a0 = fmaf(v.x, w, a0);
    a1 = fmaf(v.y, w, a1);
    a2 = fmaf(v.z, w, a2);
    a3 = fmaf(v.w, w, a3);
  }
  float4 out = {a0, a1, a2, a3};
  *reinterpret_cast<float4*>(part + ((size_t)(b*32 + ch*2 + p))*512 + e4) = out;
}

__global__ __launch_bounds__(128) void attc_reduce_kernel(
    const float* __restrict__ part, float* __restrict__ out)
{
  const int b = blockIdx.x, e4 = threadIdx.x * 4;
  float4 s = {0.f, 0.f, 0.f, 0.f};
  #pragma unroll
  for (int c = 0; c < 32; ++c) {
    float4 v = *reinterpret_cast<const float4*>(part + ((size_t)(b*32 + c))*512 + e4);
    s.x += v.x; s.y += v.y; s.z += v.z; s.w += v.w;
  }
  *reinterpret_cast<float4*>(out + b*512 + e4) = s;
}

// ---------------- launch ----------------
extern "C" void kernel_launch(void* const* d_in, const int* in_sizes, int n_in,
                              void* d_out, int out_size, void* d_ws, size_t ws_size,
                              hipStream_t stream) {
  (void)in_sizes; (void)n_in; (void)out_size; (void)ws_size;
  const float* enc       = (const float*)d_in[0];
  // d_in[1] = text_len: unused by the reference computation
  const float* dec_state = (const float*)d_in[2];
  const float* prev      = (const float*)d_in[3];
  const float* W_enc     = (const float*)d_in[4];
  const float* b_enc     = (const float*)d_in[5];
  const float* W_dec     = (const float*)d_in[6];
  const float* W_att     = (const float*)d_in[7];
  const float* conv_w    = (const float*)d_in[8];
  const float* W_out     = (const float*)d_in[9];
  // d_in[10] = b_out: additive constant in energy -> softmax-invariant, dropped

  char* ws = (char*)d_ws;
  float*          energy = (float*)(ws + 0);               // 64*2000*4 = 512000 (pad 524288)
  float*          decb   = (float*)(ws + 524288);          // 64*128*4  = 32768
  unsigned short* MTg    = (unsigned short*)(ws + 557056); // 128*32*2  = 8192
  unsigned short* WTpack = (unsigned short*)(ws + 565248); // 512*128*2 = 131072
  float*          part   = (float*)(ws + 696320);          // 64*32*512*4 = 4194304

  float* attc = (float*)d_out;             // (64, 512)
  float* attw = (float*)d_out + 64*512;    // (64, 2000)

  prep_kernel        <<<97, 256, 0, stream>>>(dec_state, W_dec, b_enc, conv_w, W_att, W_enc,
                                              decb, MTg, WTpack);
  energy_kernel      <<<dim3(32, 64), 256, 0, stream>>>(enc, prev, WTpack, MTg, decb, W_out, energy);
  softmax_kernel     <<<64, 256, 0, stream>>>(energy, attw);
  attc_partial_kernel<<<dim3(16, 64), 256, 0, stream>>>(enc, attw, part);
  attc_reduce_kernel <<<64, 128, 0, stream>>>(part, attc);
}

// Round 11
// 156.538 us; speedup vs baseline: 1.4077x; 1.4077x over previous
//
#include <hip/hip_runtime.h>
#include <hip/hip_fp16.h>

typedef _Float16 f16x8 __attribute__((ext_vector_type(8)));
typedef float f32x4 __attribute__((ext_vector_type(4)));

// B=64, T=2000, E=512, D=1024, CC=32, K=31, H=128, PAD=15

__device__ __forceinline__ unsigned short f2h(float f) {
  __half h = __float2half(f);   // v_cvt_f16_f32, RNE
  return __builtin_bit_cast(unsigned short, h);
}

__device__ __forceinline__ f16x8 u4_to_f16x8(uint4 v) {
  return __builtin_bit_cast(f16x8, v);
}

__device__ __forceinline__ f16x8 cvt8(float4 u, float4 v) {
  uint4 w;
  w.x = ((unsigned)f2h(u.y) << 16) | f2h(u.x);
  w.y = ((unsigned)f2h(u.w) << 16) | f2h(u.z);
  w.z = ((unsigned)f2h(v.y) << 16) | f2h(v.x);
  w.w = ((unsigned)f2h(v.w) << 16) | f2h(v.z);
  return u4_to_f16x8(w);
}

__device__ __forceinline__ float fast_tanh(float x) {
  return 1.f - 2.f / (__expf(2.f * x) + 1.f);   // max err ~1e-6, saturates correctly
}

// ---------------- prep: decb (fp32), MTg (f16 M^T, k-padded 32), WTpack (fragment-major f16 W_enc^T) ----------------
// WTpack: fragment (kc,ks,nt) contiguous 1 KB; lane L holds bytes [L*16, L*16+16):
//   element j of lane (lr=L&15, lg=L>>4) = W_enc[e][h], e=kc*64+ks*32+lg*8+j, h=nt*16+lr.
__global__ __launch_bounds__(256) void prep_kernel(
    const float* __restrict__ dec_state, const float* __restrict__ W_dec,
    const float* __restrict__ b_enc, const float* __restrict__ conv_w,
    const float* __restrict__ W_att, const float* __restrict__ W_enc,
    float* __restrict__ decb, unsigned short* __restrict__ MTg,
    unsigned short* __restrict__ WTpack)
{
  const int blk = blockIdx.x, tid = threadIdx.x;
  if (blk < 32) {
    __shared__ float sd[2048];
    const int sub = tid >> 7, h = tid & 127;
    const int b = blk*2 + sub;
    for (int i = h; i < 1024; i += 128) sd[sub*1024 + i] = dec_state[b*1024 + i];
    __syncthreads();
    float acc = b_enc[h];
    #pragma unroll 8
    for (int d = 0; d < 1024; ++d) acc = fmaf(sd[sub*1024 + d], W_dec[d*128 + h], acc);
    decb[b*128 + h] = acc;
  } else if (blk < 96) {
    const int e0 = (blk - 32) * 8;
    #pragma unroll
    for (int jj = 0; jj < 4; ++jj) {
      int idx = tid + jj*256;
      int el = idx >> 7, hh = idx & 127;
      int e = e0 + el;
      int kc = e >> 6, ks = (e >> 5) & 1, lg = (e >> 3) & 3, j = e & 7;
      int nt = hh >> 4, lr = hh & 15;
      int dst = (((kc*2 + ks)*8 + nt)*64 + lg*16 + lr)*8 + j;
      WTpack[dst] = f2h(W_enc[e*128 + hh]);
    }
  } else {
    if (tid < 128) {
      const int h = tid;
      for (int k = 0; k < 31; ++k) {
        float a = 0.f;
        #pragma unroll
        for (int c = 0; c < 32; ++c) a = fmaf(conv_w[c*31 + k], W_att[c*128 + h], a);
        MTg[h*32 + k] = f2h(a);
      }
      MTg[h*32 + 31] = 0;   // zero pad -> conv MFMA K=32 exact
    }
  }
}

// ---------------- energy: B fully LDS-resident, barrier-free kc loop, A-only in the vmcnt queue ----------------
// Block = 1024 threads (16 waves x 16 rows = 256 t). Stage WTpack(128KB)+MTg(8KB) to LDS once.
// Per kc: [issue 4 A(kc+1) global loads] [cvt A(kc): waits vmcnt(4)] [16 x (ds_read_b128 B + MFMA)].
// ds_read = lgkmcnt domain, ~conflict-free contiguous 1KB, transient regs -> r10's forced
// load->wait->MFMA serialization on B cannot recur.
__global__ __launch_bounds__(1024, 4) void energy_kernel(
    const float* __restrict__ enc, const float* __restrict__ prev,
    const unsigned short* __restrict__ WTpack, const unsigned short* __restrict__ MTg,
    const float* __restrict__ decb, const float* __restrict__ W_out,
    float* __restrict__ energy)
{
  extern __shared__ __align__(16) char smem[];
  unsigned short* sWT = (unsigned short*)smem;              // 131072 B
  unsigned short* sMT = (unsigned short*)(smem + 131072);   // 8192 B
  float* sPrev = (float*)(smem + 139264);                   // 288*4 = 1152 B
  float* sDecb = (float*)(smem + 140416);                   // 512 B
  float* sWout = (float*)(smem + 140928);                   // 512 B

  const int b  = blockIdx.y;
  const int t0 = blockIdx.x * 256;
  const int tid = threadIdx.x;
  const int wave = tid >> 6, lane = tid & 63;
  const int lr = lane & 15, lg = lane >> 4;

  // ---- one-time stage: B fragments + M fragments + small vectors ----
  {
    const uint4* wsrc = (const uint4*)WTpack;
    uint4* wdst = (uint4*)sWT;
    #pragma unroll
    for (int i = 0; i < 8; ++i) wdst[tid + i*1024] = wsrc[tid + i*1024];
    if (tid < 512) ((uint4*)sMT)[tid] = ((const uint4*)MTg)[tid];
    if (tid < 288) {
      int tt = t0 + tid - 15;
      sPrev[tid] = (tt >= 0 && tt < 2000) ? prev[b*2000 + tt] : 0.f;
    }
    if (tid < 128) { sDecb[tid] = decb[b*128 + tid]; sWout[tid] = W_out[tid]; }
  }
  __syncthreads();   // only barrier; waves fully independent afterwards

  const float* encB = enc + (size_t)b * (2000u*512u);
  int tg = t0 + wave*16 + lr; if (tg > 1999) tg = 1999;   // clamp; rows>=2000 never written
  const float* rowp = encB + (size_t)tg*512 + lg*8;
  const char* wlds = (const char*)sWT + lane*16;

  f32x4 acc[8];
  #pragma unroll
  for (int i = 0; i < 8; ++i) acc[i] = (f32x4){0,0,0,0};

  // prologue: A(kc=0)
  float4 c0 = *reinterpret_cast<const float4*>(rowp + 0);
  float4 c1 = *reinterpret_cast<const float4*>(rowp + 4);
  float4 c2 = *reinterpret_cast<const float4*>(rowp + 32);
  float4 c3 = *reinterpret_cast<const float4*>(rowp + 36);

  #pragma unroll
  for (int kc = 0; kc < 8; ++kc) {
    // issue A(kc+1) first -> stays in flight (vmcnt(4)) under this kc's ds+MFMA work
    float4 n0, n1, n2, n3;
    if (kc < 7) {
      const float* p = rowp + (kc+1)*64;
      n0 = *reinterpret_cast<const float4*>(p + 0);
      n1 = *reinterpret_cast<const float4*>(p + 4);
      n2 = *reinterpret_cast<const float4*>(p + 32);
      n3 = *reinterpret_cast<const float4*>(p + 36);
    }
    f16x8 a0 = cvt8(c0, c1);   // ks=0  (waits vmcnt(4): only A(kc))
    f16x8 a1 = cvt8(c2, c3);   // ks=1
    #pragma unroll
    for (int nt = 0; nt < 8; ++nt) {
      uint4 rb = *reinterpret_cast<const uint4*>(wlds + ((kc*2 + 0)*8 + nt)*1024);
      acc[nt] = __builtin_amdgcn_mfma_f32_16x16x32_f16(a0, u4_to_f16x8(rb), acc[nt], 0, 0, 0);
    }
    #pragma unroll
    for (int nt = 0; nt < 8; ++nt) {
      uint4 rb = *reinterpret_cast<const uint4*>(wlds + ((kc*2 + 1)*8 + nt)*1024);
      acc[nt] = __builtin_amdgcn_mfma_f32_16x16x32_f16(a1, u4_to_f16x8(rb), acc[nt], 0, 0, 0);
    }
    if (kc < 7) { c0 = n0; c1 = n1; c2 = n2; c3 = n3; }
  }

  // conv as MFMA from LDS (r6-r10: identical 4.88e-4 floor as fp32 conv)
  {
    f16x8 a2;
    const int pb0 = wave*16 + lr + lg*8;
    #pragma unroll
    for (int j = 0; j < 8; ++j)
      a2[j] = __builtin_bit_cast(_Float16, f2h(sPrev[pb0 + j]));
    const char* mlds = (const char*)sMT + lr*64 + lg*16;
    #pragma unroll
    for (int nt = 0; nt < 8; ++nt) {
      uint4 mv = *reinterpret_cast<const uint4*>(mlds + nt*1024);
      acc[nt] = __builtin_amdgcn_mfma_f32_16x16x32_f16(a2, u4_to_f16x8(mv), acc[nt], 0, 0, 0);
    }
  }

  // epilogue: + dec, tanh, dot W_out, reduce over h (lr)
  {
    float es0 = 0.f, es1 = 0.f, es2 = 0.f, es3 = 0.f;
    #pragma unroll
    for (int nt = 0; nt < 8; ++nt) {
      float dh = sDecb[nt*16 + lr];
      float wo = sWout[nt*16 + lr];
      es0 += fast_tanh(acc[nt][0] + dh) * wo;
      es1 += fast_tanh(acc[nt][1] + dh) * wo;
      es2 += fast_tanh(acc[nt][2] + dh) * wo;
      es3 += fast_tanh(acc[nt][3] + dh) * wo;
    }
    #pragma unroll
    for (int off = 1; off < 16; off <<= 1) {
      es0 += __shfl_xor(es0, off, 64);
      es1 += __shfl_xor(es1, off, 64);
      es2 += __shfl_xor(es2, off, 64);
      es3 += __shfl_xor(es3, off, 64);
    }
    if (lr == 0) {
      const int t = t0 + wave*16 + lg*4;
      float ev[4] = {es0, es1, es2, es3};
      #pragma unroll
      for (int r = 0; r < 4; ++r)
        if (t + r < 2000) energy[b*2000 + t + r] = ev[r];
    }
  }
}

// ---------------- softmax over T per b -> att_w ----------------
__global__ __launch_bounds__(256) void softmax_kernel(
    const float* __restrict__ energy, float* __restrict__ attw)
{
  const int b = blockIdx.x, tid = threadIdx.x;
  __shared__ float red[4];
  __shared__ float red2[4];
  float m = -1e30f;
  for (int i = tid; i < 2000; i += 256) m = fmaxf(m, energy[b*2000 + i]);
  #pragma unroll
  for (int off = 1; off < 64; off <<= 1) m = fmaxf(m, __shfl_xor(m, off, 64));
  if ((tid & 63) == 0) red[tid >> 6] = m;
  __syncthreads();
  m = fmaxf(fmaxf(red[0], red[1]), fmaxf(red[2], red[3]));

  float s = 0.f;
  for (int i = tid; i < 2000; i += 256) {
    float p = __expf(energy[b*2000 + i] - m);
    attw[b*2000 + i] = p;
    s += p;
  }
  #pragma unroll
  for (int off = 1; off < 64; off <<= 1) s += __shfl_xor(s, off, 64);
  if ((tid & 63) == 0) red2[tid >> 6] = s;
  __syncthreads();
  s = red2[0] + red2[1] + red2[2] + red2[3];
  float inv = 1.f / s;
  for (int i = tid; i < 2000; i += 256) attw[b*2000 + i] *= inv;
}

// ---------------- att_c partials: float4 loads, t-parity split (32 partials/b) ----------------
__global__ __launch_bounds__(256) void attc_partial_kernel(
    const float* __restrict__ enc, const float* __restrict__ attw,
    float* __restrict__ part)
{
  const int b = blockIdx.y, ch = blockIdx.x, tid = threadIdx.x;
  const int p = tid >> 7;
  const int e4 = (tid & 127) * 4;
  const int tstart = ch * 125 + p, tend = ch * 125 + 125;
  const float* encB = enc + (size_t)b * (2000u*512u);
  float a0 = 0.f, a1 = 0.f, a2 = 0.f, a3 = 0.f;
  #pragma unroll 2
  for (int t = tstart; t < tend; t += 2) {
    float w = attw[b*2000 + t];
    float4 v = *reinterpret_cast<const float4*>(encB + (size_t)t*512 + e4);
    a0 = fmaf(v.x, w, a0);
    a1 = fmaf(v.y, w, a1);
    a2 = fmaf(v.z, w, a2);
    a3 = fmaf(v.w, w, a3);
  }
  float4 out = {a0, a1, a2, a3};
  *reinterpret_cast<float4*>(part + ((size_t)(b*32 + ch*2 + p))*512 + e4) = out;
}

__global__ __launch_bounds__(128) void attc_reduce_kernel(
    const float* __restrict__ part, float* __restrict__ out)
{
  const int b = blockIdx.x, e4 = threadIdx.x * 4;
  float4 s = {0.f, 0.f, 0.f, 0.f};
  #pragma unroll
  for (int c = 0; c < 32; ++c) {
    float4 v = *reinterpret_cast<const float4*>(part + ((size_t)(b*32 + c))*512 + e4);
    s.x += v.x; s.y += v.y; s.z += v.z; s.w += v.w;
  }
  *reinterpret_cast<float4*>(out + b*512 + e4) = s;
}

// ---------------- launch ----------------
extern "C" void kernel_launch(void* const* d_in, const int* in_sizes, int n_in,
                              void* d_out, int out_size, void* d_ws, size_t ws_size,
                              hipStream_t stream) {
  (void)in_sizes; (void)n_in; (void)out_size; (void)ws_size;
  const float* enc       = (const float*)d_in[0];
  // d_in[1] = text_len: unused by the reference computation
  const float* dec_state = (const float*)d_in[2];
  const float* prev      = (const float*)d_in[3];
  const float* W_enc     = (const float*)d_in[4];
  const float* b_enc     = (const float*)d_in[5];
  const float* W_dec     = (const float*)d_in[6];
  const float* W_att     = (const float*)d_in[7];
  const float* conv_w    = (const float*)d_in[8];
  const float* W_out     = (const float*)d_in[9];
  // d_in[10] = b_out: additive constant in energy -> softmax-invariant, dropped

  char* ws = (char*)d_ws;
  float*          energy = (float*)(ws + 0);               // 64*2000*4 = 512000 (pad 524288)
  float*          decb   = (float*)(ws + 524288);          // 64*128*4  = 32768
  unsigned short* MTg    = (unsigned short*)(ws + 557056); // 128*32*2  = 8192
  unsigned short* WTpack = (unsigned short*)(ws + 565248); // 512*128*2 = 131072
  float*          part   = (float*)(ws + 696320);          // 64*32*512*4 = 4194304

  float* attc = (float*)d_out;             // (64, 512)
  float* attw = (float*)d_out + 64*512;    // (64, 2000)

  const int lds_bytes = 141440;   // 128K WT + 8K MT + prev/dec/wout

  prep_kernel        <<<97, 256, 0, stream>>>(dec_state, W_dec, b_enc, conv_w, W_att, W_enc,
                                              decb, MTg, WTpack);
  energy_kernel      <<<dim3(8, 64), 1024, lds_bytes, stream>>>(enc, prev, WTpack, MTg, decb, W_out, energy);
  softmax_kernel     <<<64, 256, 0, stream>>>(energy, attw);
  attc_partial_kernel<<<dim3(16, 64), 256, 0, stream>>>(enc, attw, part);
  attc_reduce_kernel <<<64, 128, 0, stream>>>(part, attc);
}